// Round 5
// baseline (885.808 us; speedup 1.0000x reference)
//
#include <hip/hip_runtime.h>
#include <hip/hip_bf16.h>

typedef __hip_bfloat16 bf16;
typedef __attribute__((ext_vector_type(8))) __bf16 bfrag;   // MFMA A/B operand
typedef __attribute__((ext_vector_type(4))) float f32x4;    // MFMA C/D

#define N_NODES 50000
#define N_EDGES 800000
#define GB_GEMM 782            // 2 col-tiles x 391 row-tiles (layer-1 GEMM)
#define GB_PLACE 3125          // ceil(800000/256)

__device__ __forceinline__ unsigned short f2bf(float f) {
    bf16 h = __float2bfloat16(f);
    return *reinterpret_cast<unsigned short*>(&h);
}

__device__ __forceinline__ uint4 zero4() { uint4 z; z.x = z.y = z.z = z.w = 0u; return z; }

__device__ __forceinline__ void load_edge(const int* __restrict__ ei, int fl64,
                                          int e, int& s, int& d) {
    if (fl64) {
        int2 a = ((const int2*)ei)[e];
        int2 b = ((const int2*)ei)[N_EDGES + e];
        s = a.x; d = b.x;
    } else {
        s = ei[e];
        d = ei[N_EDGES + e];
    }
}

__device__ __forceinline__ float rdf(const void* p, int off, int f32) {
    return f32 ? ((const float*)p)[off] : (float)((const bf16*)p)[off];
}

// ---------------------------------------------------------------------------
// detect + zero
// ---------------------------------------------------------------------------
__global__ void detect_zero_kernel(const unsigned short* __restrict__ xb,
                                   const int* __restrict__ ei,
                                   int* __restrict__ flags,
                                   int* __restrict__ cnt) {   // 2*N_NODES ints
    int i = blockIdx.x * 256 + threadIdx.x;
    if (i < 2 * N_NODES) cnt[i] = 0;
    if (blockIdx.x == 0) {
        __shared__ int s_insane, s_nonzero;
        int t = threadIdx.x;
        if (t == 0) { s_insane = 0; s_nonzero = 0; }
        __syncthreads();
        unsigned short h = xb[2 * t];
        int e = (h >> 7) & 0xFF;
        if (!(e == 0 || (e >= 90 && e <= 150))) atomicOr(&s_insane, 1);
        if (ei[2 * t + 1] != 0) atomicOr(&s_nonzero, 1);
        __syncthreads();
        if (t == 0) { flags[0] = s_insane ? 1 : 0; flags[1] = s_nonzero ? 0 : 1; }
    }
}

// ---------------------------------------------------------------------------
// Unified weight/bias conversion.
// ---------------------------------------------------------------------------
__global__ void cvt_all_kernel(const void* W1, const void* W2, const void* W3,
                               const void* mW1, const void* mW2,
                               const void* b1, const void* b2, const void* b3,
                               const void* mb1, const void* mb2,
                               const int* __restrict__ flags,
                               unsigned short* __restrict__ WT,
                               float* __restrict__ biasd) {
    int i = blockIdx.x * 256 + threadIdx.x;
    if (i >= 176896) return;
    const int f32 = flags[0];
    if (i < 163840) {
        const void* s; int local, N;
        if      (i <  65536) { s = W1; local = i;          N = 256; }
        else if (i < 131072) { s = W2; local = i -  65536; N = 256; }
        else                 { s = W3; local = i - 131072; N = 128; }
        int n = local >> 8, k = local & 255;
        WT[i] = f2bf(rdf(s, k * N + n, f32));
    } else if (i < 172032) {
        int local = i - 163840;
        int n = local >> 7, k = local & 127;
        WT[i] = f2bf(rdf(mW1, k * 64 + n, f32));
    } else if (i < 176128) {
        int local = i - 172032;
        int n = local >> 6, k = local & 63;
        WT[i] = f2bf(rdf(mW2, k * 64 + n, f32));
    } else {
        int local = i - 176128;
        const void* s; int off;
        if      (local < 256) { s = b1;  off = local; }
        else if (local < 512) { s = b2;  off = local - 256; }
        else if (local < 640) { s = b3;  off = local - 512; }
        else if (local < 704) { s = mb1; off = local - 640; }
        else                  { s = mb2; off = local - 704; }
        biasd[local] = rdf(s, off, f32);
    }
}

__device__ __forceinline__ uint4 ld8_bf16(const unsigned short* p) {
    return *(const uint4*)p;
}
__device__ __forceinline__ uint4 ld8_f32(const float* p) {
    float4 a = *(const float4*)(p);
    float4 b = *(const float4*)(p + 4);
    uint4 r;
    r.x = ((unsigned)f2bf(a.y) << 16) | f2bf(a.x);
    r.y = ((unsigned)f2bf(a.w) << 16) | f2bf(a.z);
    r.z = ((unsigned)f2bf(b.y) << 16) | f2bf(b.x);
    r.w = ((unsigned)f2bf(b.w) << 16) | f2bf(b.z);
    return r;
}

// ---------------------------------------------------------------------------
// Conv GEMM body: C_bf16[M][N] = bf16((X @ W) * rowscale), fp32 accum, K=256.
// PRESCALE: multiply output row by rsqrt(outdeg) so the NEXT gather is a pure
// sum (diagonal scaling commutes with aggregation).
// ---------------------------------------------------------------------------
template <bool DUALX, bool PRESCALE>
__device__ __forceinline__ void gemm_body(
        unsigned short (*Xs)[40], unsigned short (*Ws)[40],
        const void* __restrict__ Xv, const int* __restrict__ flags,
        const unsigned short* __restrict__ WT,
        const int* __restrict__ cntS,
        unsigned short* __restrict__ C,
        int bx, int by, int M, int N) {
    constexpr int K = 256;
    const int tid  = threadIdx.x;
    const int lane = tid & 63;
    const int w    = tid >> 6;
    const int wr   = (w >> 1) * 64;
    const int wc   = (w & 1) * 64;
    const int lrow = lane & 15;
    const int koff = (lane >> 4) * 8;
    const int row0 = by * 128;
    const int col0 = bx * 128;
    const bool xf32 = DUALX && (flags[0] != 0);
    const unsigned short* Xb = (const unsigned short*)Xv;
    const float* Xf = (const float*)Xv;

    const int r0 = tid >> 2, q0 = tid & 3;
    const int r1 = r0 + 64;
    const int gr0 = row0 + r0, gr1 = row0 + r1;

    uint4 xv0, xv1, wv0, wv1;
    {
        int e = q0 * 8;
        xv0 = (gr0 < M) ? (xf32 ? ld8_f32(Xf + (size_t)gr0 * K + e)
                                : ld8_bf16(Xb + (size_t)gr0 * K + e)) : zero4();
        xv1 = (gr1 < M) ? (xf32 ? ld8_f32(Xf + (size_t)gr1 * K + e)
                                : ld8_bf16(Xb + (size_t)gr1 * K + e)) : zero4();
        wv0 = *(const uint4*)(WT + (size_t)(col0 + r0) * K + e);
        wv1 = *(const uint4*)(WT + (size_t)(col0 + r1) * K + e);
    }

    f32x4 acc[4][4] = {};

    for (int k0 = 0; k0 < K; k0 += 32) {
        *(uint4*)&Xs[r0][q0 * 8] = xv0;
        *(uint4*)&Xs[r1][q0 * 8] = xv1;
        *(uint4*)&Ws[r0][q0 * 8] = wv0;
        *(uint4*)&Ws[r1][q0 * 8] = wv1;
        __syncthreads();

        const int k1 = k0 + 32;
        if (k1 < K) {
            int e = k1 + q0 * 8;
            xv0 = (gr0 < M) ? (xf32 ? ld8_f32(Xf + (size_t)gr0 * K + e)
                                    : ld8_bf16(Xb + (size_t)gr0 * K + e)) : zero4();
            xv1 = (gr1 < M) ? (xf32 ? ld8_f32(Xf + (size_t)gr1 * K + e)
                                    : ld8_bf16(Xb + (size_t)gr1 * K + e)) : zero4();
            wv0 = *(const uint4*)(WT + (size_t)(col0 + r0) * K + e);
            wv1 = *(const uint4*)(WT + (size_t)(col0 + r1) * K + e);
        }

        bfrag af[4], bv[4];
#pragma unroll
        for (int i = 0; i < 4; i++)
            af[i] = *(const bfrag*)&Xs[wr + i * 16 + lrow][koff];
#pragma unroll
        for (int j = 0; j < 4; j++)
            bv[j] = *(const bfrag*)&Ws[wc + j * 16 + lrow][koff];
#pragma unroll
        for (int i = 0; i < 4; i++)
#pragma unroll
            for (int j = 0; j < 4; j++)
                acc[i][j] = __builtin_amdgcn_mfma_f32_16x16x32_bf16(
                    af[i], bv[j], acc[i][j], 0, 0, 0);
        __syncthreads();
    }

#pragma unroll
    for (int i = 0; i < 4; i++) {
#pragma unroll
        for (int r = 0; r < 4; r++) {
            int row = row0 + wr + i * 16 + ((lane >> 4) * 4) + r;
            if (row >= M) continue;
            const float s = PRESCALE ? rsqrtf((float)max(cntS[row], 1)) : 1.0f;
#pragma unroll
            for (int j = 0; j < 4; j++) {
                int col = col0 + wc + j * 16 + lrow;
                C[(size_t)row * N + col] = f2bf(acc[i][j][r] * s);
            }
        }
    }
}

// ---------------------------------------------------------------------------
// Mega kernel A (round-0 order, proven ~97us): GEMM blocks first (BW-bound),
// place blocks after (atomic-bound); the atomic EA traffic (~100MB, intrinsic
// to device-scope RMWs) hides under the GEMM stream.  Place-first was 131us.
// ---------------------------------------------------------------------------
__launch_bounds__(256)
__global__ void megaA_kernel(const void* __restrict__ x,
                             const int* __restrict__ ei,
                             const int* __restrict__ flags,
                             const unsigned short* __restrict__ WT,
                             unsigned short* __restrict__ Hbf,
                             int* __restrict__ cntS, int* __restrict__ cntD,
                             unsigned short* __restrict__ esrc_pad, int M) {
    __shared__ unsigned short Xs[128][40];
    __shared__ unsigned short Ws[128][40];
    const int bid = blockIdx.x;
    if (bid < GB_GEMM) {
        gemm_body<true, false>(Xs, Ws, x, flags, WT, nullptr, Hbf,
                               bid & 1, bid >> 1, M, 256);
    } else {
        int e = (bid - GB_GEMM) * 256 + threadIdx.x;
        if (e < N_EDGES) {
            int s, d; load_edge(ei, flags[1], e, s, d);
            atomicAdd(&cntS[s], 1);
            int pos = atomicAdd(&cntD[d], 1);
            if (pos < 64)
                __builtin_nontemporal_store((unsigned short)s,
                                            &esrc_pad[(d << 6) + pos]);
        }
    }
}

// ---------------------------------------------------------------------------
// Sort each node's src list ascending (64-elem bitonic, one wave/node, shfl).
// Needed by the TILED gathers: a sorted list makes each src-tile a contiguous
// segment consumed by a running pointer (no rescans).  Permutation of a sum
// -> correctness-neutral.  Sentinel 0xFFFF pads lanes >= cn.
// ---------------------------------------------------------------------------
__launch_bounds__(256)
__global__ void sort_kernel(const int* __restrict__ cntD,
                            unsigned short* __restrict__ esrc_pad, int nNodes) {
    const int node = blockIdx.x * 4 + (threadIdx.x >> 6);
    const int lane = threadIdx.x & 63;
    if (node >= nNodes) return;
    unsigned short* ep = esrc_pad + (node << 6);
    const int cn = min(cntD[node], 64);
    unsigned v = (lane < cn) ? (unsigned)ep[lane] : 0xFFFFu;
#pragma unroll
    for (int k = 2; k <= 64; k <<= 1) {
#pragma unroll
        for (int m = k >> 1; m >= 1; m >>= 1) {
            unsigned p = __shfl_xor(v, m, 64);
            bool lower = (lane & m) == 0;
            bool asc   = (lane & k) == 0;
            unsigned lo = v < p ? v : p;
            unsigned hi = v < p ? p : v;
            v = (asc == lower) ? lo : hi;
        }
    }
    if (lane < cn) ep[lane] = (unsigned short)v;
}

// ---------------------------------------------------------------------------
// Accumulation helpers.
// ---------------------------------------------------------------------------
__device__ __forceinline__ void accs(unsigned int u, float s, float& a0, float& a1) {
    a0 = fmaf(s, __uint_as_float(u << 16), a0);
    a1 = fmaf(s, __uint_as_float(u & 0xffff0000u), a1);
}
__device__ __forceinline__ void acc4s(uint4 u, float s, float (&a)[8]) {
    accs(u.x, s, a[0], a[1]); accs(u.y, s, a[2], a[3]);
    accs(u.z, s, a[4], a[5]); accs(u.w, s, a[6], a[7]);
}

// ---------------------------------------------------------------------------
// SRC-TILED gather:  Y[n,:] = relu( sIn[n]*(sum_e [sOut]*H[src,:]) + bias )
// Each LQ-lane group owns NPG=8 consecutive nodes; all 8 fp32 accumulators
// live in registers (8x8=64 VGPR).  OUTER loop over src tiles of TROWS rows
// (~3MB, fits one XCD L2); per tile each node consumes the contiguous sorted-
// list segment in [t0,t0+TROWS) via a running pointer.  Grid ~= one residency
// wave -> all groups sweep tiles together -> tile stays L2-hot (vs ~50% L2
// hit for the random full-range gather; latency drops ~4x too).
// ESCALE: per-edge rsqrt(cntS[src]) (layer 1 only; cntS is 200KB, L2-hot).
// OUT: 0 = bf16 only; 2 = fp32 + bf16 mirror.
// ---------------------------------------------------------------------------
template <int LQ, bool ESCALE, int OUT, int TROWS>
__launch_bounds__(256)
__global__ void gather_tiled_kernel(const int* __restrict__ cntD,
                                    const int* __restrict__ cntS,
                                    const unsigned short* __restrict__ esrc_pad,
                                    const unsigned short* __restrict__ H,
                                    const float* __restrict__ bias,
                                    float* __restrict__ Yf,
                                    unsigned short* __restrict__ Yb, int M) {
    constexpr int NPG = 8;
    constexpr int GPB = 256 / LQ;
    constexpr int D = LQ * 8;
    const int g    = blockIdx.x * GPB + threadIdx.x / LQ;
    const int lane = threadIdx.x % LQ;
    const int node0 = g * NPG;
    if (node0 >= M) return;
    const uint4* __restrict__ H4 = (const uint4*)H;

    float acc[NPG][8] = {};
    int ptr[NPG], cn[NPG];
#pragma unroll
    for (int i = 0; i < NPG; i++) {
        const int nd = node0 + i;
        cn[i] = (nd < M) ? min(cntD[nd], 64) : 0;
        ptr[i] = 0;
    }

    for (int t0 = 0; t0 < M; t0 += TROWS) {
        const int tEnd = t0 + TROWS;
#pragma unroll
        for (int i = 0; i < NPG; i++) {
            const unsigned short* ep = esrc_pad + ((size_t)(node0 + i) << 6);
            int j = ptr[i];
            const int c = cn[i];
            while (j + 4 <= c) {
                const int s0 = ep[j], s1 = ep[j + 1], s2 = ep[j + 2], s3 = ep[j + 3];
                if (s3 >= tEnd) break;
                float w0 = 1.f, w1 = 1.f, w2 = 1.f, w3 = 1.f;
                if (ESCALE) {
                    w0 = rsqrtf((float)max(cntS[s0], 1));
                    w1 = rsqrtf((float)max(cntS[s1], 1));
                    w2 = rsqrtf((float)max(cntS[s2], 1));
                    w3 = rsqrtf((float)max(cntS[s3], 1));
                }
                uint4 u0 = H4[(size_t)s0 * LQ + lane];
                uint4 u1 = H4[(size_t)s1 * LQ + lane];
                uint4 u2 = H4[(size_t)s2 * LQ + lane];
                uint4 u3 = H4[(size_t)s3 * LQ + lane];
                acc4s(u0, w0, acc[i]); acc4s(u1, w1, acc[i]);
                acc4s(u2, w2, acc[i]); acc4s(u3, w3, acc[i]);
                j += 4;
            }
            while (j < c) {
                const int s0 = ep[j];
                if (s0 >= tEnd) break;
                const float w0 = ESCALE ? rsqrtf((float)max(cntS[s0], 1)) : 1.f;
                uint4 u = H4[(size_t)s0 * LQ + lane];
                acc4s(u, w0, acc[i]);
                j++;
            }
            ptr[i] = j;
        }
    }

#pragma unroll
    for (int i = 0; i < NPG; i++) {
        const int nd = node0 + i;
        if (nd >= M) continue;
        const float sc = rsqrtf((float)max(cntD[nd], 1));
        const float* bp = bias + lane * 8;
        float4 b0 = *(const float4*)(bp);
        float4 b1 = *(const float4*)(bp + 4);
        float r0 = fmaxf(fmaf(acc[i][0], sc, b0.x), 0.0f);
        float r1 = fmaxf(fmaf(acc[i][1], sc, b0.y), 0.0f);
        float r2 = fmaxf(fmaf(acc[i][2], sc, b0.z), 0.0f);
        float r3 = fmaxf(fmaf(acc[i][3], sc, b0.w), 0.0f);
        float r4 = fmaxf(fmaf(acc[i][4], sc, b1.x), 0.0f);
        float r5 = fmaxf(fmaf(acc[i][5], sc, b1.y), 0.0f);
        float r6 = fmaxf(fmaf(acc[i][6], sc, b1.z), 0.0f);
        float r7 = fmaxf(fmaf(acc[i][7], sc, b1.w), 0.0f);
        if (OUT == 2) {
            float* yp = Yf + (size_t)nd * D + lane * 8;
            float4 o0 = {r0, r1, r2, r3};
            float4 o1 = {r4, r5, r6, r7};
            *(float4*)(yp)     = o0;
            *(float4*)(yp + 4) = o1;
        }
        unsigned short* yp = Yb + (size_t)nd * D + lane * 8;
        ushort4 o0, o1;
        o0.x = f2bf(r0); o0.y = f2bf(r1); o0.z = f2bf(r2); o0.w = f2bf(r3);
        o1.x = f2bf(r4); o1.y = f2bf(r5); o1.z = f2bf(r6); o1.w = f2bf(r7);
        *(ushort4*)(yp)     = o0;
        *(ushort4*)(yp + 4) = o1;
    }
}

// Plain conv GEMM (layers 2,3) with output pre-scale by rsqrt(outdeg).
__launch_bounds__(256)
__global__ void mfma_gemm_kernel(const unsigned short* __restrict__ X,
                                 const int* __restrict__ flags,
                                 const unsigned short* __restrict__ WT,
                                 const int* __restrict__ cntS,
                                 unsigned short* __restrict__ C,
                                 int M, int N) {
    __shared__ unsigned short Xs[128][40];
    __shared__ unsigned short Ws[128][40];
    gemm_body<false, true>(Xs, Ws, X, flags, WT, cntS, C,
                           blockIdx.x, blockIdx.y, M, N);
}

// ---------------------------------------------------------------------------
// Fused MLP head:  out[M][64] = relu(X[M][128] @ mW1 + mb1) @ mW2 + mb2
// ---------------------------------------------------------------------------
__launch_bounds__(256)
__global__ void mfma_mlp2_kernel(const unsigned short* __restrict__ X,
                                 const unsigned short* __restrict__ WT1, // [64][128]
                                 const unsigned short* __restrict__ WT2, // [64][64]
                                 const float* __restrict__ b1,
                                 const float* __restrict__ b2,
                                 float* __restrict__ out, int M) {
    __shared__ unsigned short Xs[128][136];
    __shared__ unsigned short W1s[64][136];
    __shared__ unsigned short W2s[64][72];
    const int tid  = threadIdx.x;
    const int lane = tid & 63;
    const int w    = tid >> 6;
    const int lrow = lane & 15;
    const int koff = (lane >> 4) * 8;
    const int row0 = blockIdx.x * 128;

#pragma unroll
    for (int i = 0; i < 8; i++) {
        int c = tid + i * 256;
        int r = c >> 4, q = c & 15;
        int gr = row0 + r;
        uint4 v = (gr < M) ? *(const uint4*)(X + (size_t)gr * 128 + q * 8) : zero4();
        *(uint4*)&Xs[r][q * 8] = v;
    }
#pragma unroll
    for (int i = 0; i < 4; i++) {
        int c = tid + i * 256;
        int n = c >> 4, q = c & 15;
        *(uint4*)&W1s[n][q * 8] = *(const uint4*)(WT1 + (size_t)n * 128 + q * 8);
    }
#pragma unroll
    for (int i = 0; i < 2; i++) {
        int c = tid + i * 256;
        int n = c >> 3, q = c & 7;
        *(uint4*)&W2s[n][q * 8] = *(const uint4*)(WT2 + (size_t)n * 64 + q * 8);
    }
    __syncthreads();

    f32x4 acc[2][4] = {};
#pragma unroll
    for (int k0 = 0; k0 < 128; k0 += 32) {
        bfrag af[2], bv[4];
#pragma unroll
        for (int i = 0; i < 2; i++)
            af[i] = *(const bfrag*)&Xs[w * 32 + i * 16 + lrow][k0 + koff];
#pragma unroll
        for (int j = 0; j < 4; j++)
            bv[j] = *(const bfrag*)&W1s[j * 16 + lrow][k0 + koff];
#pragma unroll
        for (int i = 0; i < 2; i++)
#pragma unroll
            for (int j = 0; j < 4; j++)
                acc[i][j] = __builtin_amdgcn_mfma_f32_16x16x32_bf16(
                    af[i], bv[j], acc[i][j], 0, 0, 0);
    }
    __syncthreads();

#pragma unroll
    for (int i = 0; i < 2; i++) {
#pragma unroll
        for (int r = 0; r < 4; r++) {
            int row = w * 32 + i * 16 + ((lane >> 4) * 4) + r;
#pragma unroll
            for (int j = 0; j < 4; j++) {
                int col = j * 16 + lrow;
                Xs[row][col] = f2bf(fmaxf(acc[i][j][r] + b1[col], 0.0f));
            }
        }
    }
    __syncthreads();

    f32x4 acc2[2][4] = {};
#pragma unroll
    for (int k0 = 0; k0 < 64; k0 += 32) {
        bfrag af[2], bv[4];
#pragma unroll
        for (int i = 0; i < 2; i++)
            af[i] = *(const bfrag*)&Xs[w * 32 + i * 16 + lrow][k0 + koff];
#pragma unroll
        for (int j = 0; j < 4; j++)
            bv[j] = *(const bfrag*)&W2s[j * 16 + lrow][k0 + koff];
#pragma unroll
        for (int i = 0; i < 2; i++)
#pragma unroll
            for (int j = 0; j < 4; j++)
                acc2[i][j] = __builtin_amdgcn_mfma_f32_16x16x32_bf16(
                    af[i], bv[j], acc2[i][j], 0, 0, 0);
    }

#pragma unroll
    for (int i = 0; i < 2; i++) {
#pragma unroll
        for (int r = 0; r < 4; r++) {
            int row = row0 + w * 32 + i * 16 + ((lane >> 4) * 4) + r;
            if (row >= M) continue;
#pragma unroll
            for (int j = 0; j < 4; j++) {
                int col = j * 16 + lrow;
                out[(size_t)row * 64 + col] = acc2[i][j][r] + b2[col];
            }
        }
    }
}

// ---------------------------------------------------------------------------
extern "C" void kernel_launch(void* const* d_in, const int* in_sizes, int n_in,
                              void* d_out, int out_size, void* d_ws, size_t ws_size,
                              hipStream_t stream) {
    const void* x  = d_in[0];
    const int*  ei = (const int*)d_in[1];
    const void *W1 = d_in[2],  *b1 = d_in[3];
    const void *W2 = d_in[4],  *b2 = d_in[5];
    const void *W3 = d_in[6],  *b3 = d_in[7];
    const void *mW1 = d_in[8], *mb1 = d_in[9];
    const void *mW2 = d_in[10],*mb2 = d_in[11];

    // Output: fp32 concatenated (out[50000x64], h_last[50000x128])
    float* out   = (float*)d_out;
    float* out_h = out + (size_t)N_NODES * 64;

    float* ws = (float*)d_ws;
    size_t off = 0;
    int*   flags  = (int*)(ws + off); off += 64;
    int*   cntS   = (int*)(ws + off); off += N_NODES;        // zeroed together
    int*   cntD   = (int*)(ws + off); off += N_NODES;
    unsigned short* esrc_p = (unsigned short*)(ws + off);
    off += (size_t)N_NODES * 32;                             // 50000*64 ushorts
    float* biasd  = ws + off;         off += 768;
    // bias offsets: b1@0 b2@256 b3@512 mb1@640 mb2@704
    off = (off + 63) & ~(size_t)63;
    unsigned short* WT  = (unsigned short*)(ws + off); off += 88448;  // 176896 u16
    // WT segments: conv@0, mWT1@163840, mWT2@172032
    unsigned short* Gbf = (unsigned short*)(ws + off); off += (size_t)N_NODES * 128;
    unsigned short* Hbf = (unsigned short*)(ws + off); off += (size_t)N_NODES * 128;
    unsigned short* hob = (unsigned short*)(ws + off); off += (size_t)N_NODES * 64;  // h_last bf16

    const int M = N_NODES;
    const dim3 blk(256);
    const int gy128 = (M + 127) / 128;        // 391

    // 1) detect + zero counters
    detect_zero_kernel<<<391, blk, 0, stream>>>(
        (const unsigned short*)x, ei, flags, cntS);

    // 2) weight/bias conversion
    cvt_all_kernel<<<(176896 + 255) / 256, blk, 0, stream>>>(
        W1, W2, W3, mW1, mW2, b1, b2, b3, mb1, mb2, flags, WT, biasd);

    // 3) megaA: layer-1 GEMM (x@W1 -> Hbf) || padded-CSR build (GEMM first)
    megaA_kernel<<<GB_GEMM + GB_PLACE, blk, 0, stream>>>(
        x, ei, flags, WT, Hbf, cntS, cntD, esrc_p, M);

    // 3b) sort per-node src lists (enables tiled segment walk)
    sort_kernel<<<(M + 3) / 4, blk, 0, stream>>>(cntD, esrc_p, M);

    // 4) g1 tiled (ESCALE; H1 unscaled) -> Gbf.  782 blocks ~= 1 residency wave.
    gather_tiled_kernel<32, true, 0, 6144><<<782, blk, 0, stream>>>(
        cntD, cntS, esrc_p, Hbf, biasd, nullptr, Gbf, M);

    // 5) layer 2 GEMM (pre-scaled output) + tiled pure-sum gather
    mfma_gemm_kernel<<<dim3(2, gy128), blk, 0, stream>>>(
        Gbf, flags, WT + 65536, cntS, Hbf, M, 256);
    gather_tiled_kernel<32, false, 0, 6144><<<782, blk, 0, stream>>>(
        cntD, cntS, esrc_p, Hbf, biasd + 256, nullptr, Gbf, M);

    // 6) layer 3 GEMM (N=128, pre-scaled) + tiled gather -> out_h fp32 + hob
    mfma_gemm_kernel<<<dim3(1, gy128), blk, 0, stream>>>(
        Gbf, flags, WT + 131072, cntS, Hbf, M, 128);
    gather_tiled_kernel<16, false, 2, 12288><<<391, blk, 0, stream>>>(
        cntD, nullptr, esrc_p, Hbf, biasd + 512, out_h, hob, M);

    // 7) MLP head fused: out = relu(hob @ mW1 + mb1) @ mW2 + mb2
    mfma_mlp2_kernel<<<gy128, blk, 0, stream>>>(
        hob, WT + 163840, WT + 172032, biasd + 640, biasd + 704, out, M);
}

// Round 6
// 389.572 us; speedup vs baseline: 2.2738x; 2.2738x over previous
//
#include <hip/hip_runtime.h>
#include <hip/hip_bf16.h>

typedef __hip_bfloat16 bf16;
typedef __attribute__((ext_vector_type(8))) __bf16 bfrag;   // MFMA A/B operand
typedef __attribute__((ext_vector_type(4))) float f32x4;    // MFMA C/D

#define N_NODES 50000
#define N_EDGES 800000
#define GB_GEMM 782            // 2 col-tiles x 391 row-tiles (layer-1 GEMM)
#define GB_PLACE 3125          // ceil(800000/256)

__device__ __forceinline__ unsigned short f2bf(float f) {
    bf16 h = __float2bfloat16(f);
    return *reinterpret_cast<unsigned short*>(&h);
}

__device__ __forceinline__ uint4 zero4() { uint4 z; z.x = z.y = z.z = z.w = 0u; return z; }

__device__ __forceinline__ void load_edge(const int* __restrict__ ei, int fl64,
                                          int e, int& s, int& d) {
    if (fl64) {
        int2 a = ((const int2*)ei)[e];
        int2 b = ((const int2*)ei)[N_EDGES + e];
        s = a.x; d = b.x;
    } else {
        s = ei[e];
        d = ei[N_EDGES + e];
    }
}

__device__ __forceinline__ float rdf(const void* p, int off, int f32) {
    return f32 ? ((const float*)p)[off] : (float)((const bf16*)p)[off];
}

// ---------------------------------------------------------------------------
// detect + zero
// ---------------------------------------------------------------------------
__global__ void detect_zero_kernel(const unsigned short* __restrict__ xb,
                                   const int* __restrict__ ei,
                                   int* __restrict__ flags,
                                   int* __restrict__ cnt) {   // 2*N_NODES ints
    int i = blockIdx.x * 256 + threadIdx.x;
    if (i < 2 * N_NODES) cnt[i] = 0;
    if (blockIdx.x == 0) {
        __shared__ int s_insane, s_nonzero;
        int t = threadIdx.x;
        if (t == 0) { s_insane = 0; s_nonzero = 0; }
        __syncthreads();
        unsigned short h = xb[2 * t];
        int e = (h >> 7) & 0xFF;
        if (!(e == 0 || (e >= 90 && e <= 150))) atomicOr(&s_insane, 1);
        if (ei[2 * t + 1] != 0) atomicOr(&s_nonzero, 1);
        __syncthreads();
        if (t == 0) { flags[0] = s_insane ? 1 : 0; flags[1] = s_nonzero ? 0 : 1; }
    }
}

// ---------------------------------------------------------------------------
// Unified weight/bias conversion.
// ---------------------------------------------------------------------------
__global__ void cvt_all_kernel(const void* W1, const void* W2, const void* W3,
                               const void* mW1, const void* mW2,
                               const void* b1, const void* b2, const void* b3,
                               const void* mb1, const void* mb2,
                               const int* __restrict__ flags,
                               unsigned short* __restrict__ WT,
                               float* __restrict__ biasd) {
    int i = blockIdx.x * 256 + threadIdx.x;
    if (i >= 176896) return;
    const int f32 = flags[0];
    if (i < 163840) {
        const void* s; int local, N;
        if      (i <  65536) { s = W1; local = i;          N = 256; }
        else if (i < 131072) { s = W2; local = i -  65536; N = 256; }
        else                 { s = W3; local = i - 131072; N = 128; }
        int n = local >> 8, k = local & 255;
        WT[i] = f2bf(rdf(s, k * N + n, f32));
    } else if (i < 172032) {
        int local = i - 163840;
        int n = local >> 7, k = local & 127;
        WT[i] = f2bf(rdf(mW1, k * 64 + n, f32));
    } else if (i < 176128) {
        int local = i - 172032;
        int n = local >> 6, k = local & 63;
        WT[i] = f2bf(rdf(mW2, k * 64 + n, f32));
    } else {
        int local = i - 176128;
        const void* s; int off;
        if      (local < 256) { s = b1;  off = local; }
        else if (local < 512) { s = b2;  off = local - 256; }
        else if (local < 640) { s = b3;  off = local - 512; }
        else if (local < 704) { s = mb1; off = local - 640; }
        else                  { s = mb2; off = local - 704; }
        biasd[local] = rdf(s, off, f32);
    }
}

__device__ __forceinline__ uint4 ld8_bf16(const unsigned short* p) {
    return *(const uint4*)p;
}
__device__ __forceinline__ uint4 ld8_f32(const float* p) {
    float4 a = *(const float4*)(p);
    float4 b = *(const float4*)(p + 4);
    uint4 r;
    r.x = ((unsigned)f2bf(a.y) << 16) | f2bf(a.x);
    r.y = ((unsigned)f2bf(a.w) << 16) | f2bf(a.z);
    r.z = ((unsigned)f2bf(b.y) << 16) | f2bf(b.x);
    r.w = ((unsigned)f2bf(b.w) << 16) | f2bf(b.z);
    return r;
}

// ---------------------------------------------------------------------------
// Conv GEMM body: C_bf16[M][N] = bf16((X @ W) * rowscale), fp32 accum, K=256.
// PRESCALE: multiply output row by rsqrt(outdeg) so the NEXT gather is a pure
// sum (diagonal scaling commutes with the linear aggregation).
// ---------------------------------------------------------------------------
template <bool DUALX, bool PRESCALE>
__device__ __forceinline__ void gemm_body(
        unsigned short (*Xs)[40], unsigned short (*Ws)[40],
        const void* __restrict__ Xv, const int* __restrict__ flags,
        const unsigned short* __restrict__ WT,
        const int* __restrict__ cntS,
        unsigned short* __restrict__ C,
        int bx, int by, int M, int N) {
    constexpr int K = 256;
    const int tid  = threadIdx.x;
    const int lane = tid & 63;
    const int w    = tid >> 6;
    const int wr   = (w >> 1) * 64;
    const int wc   = (w & 1) * 64;
    const int lrow = lane & 15;
    const int koff = (lane >> 4) * 8;
    const int row0 = by * 128;
    const int col0 = bx * 128;
    const bool xf32 = DUALX && (flags[0] != 0);
    const unsigned short* Xb = (const unsigned short*)Xv;
    const float* Xf = (const float*)Xv;

    const int r0 = tid >> 2, q0 = tid & 3;
    const int r1 = r0 + 64;
    const int gr0 = row0 + r0, gr1 = row0 + r1;

    uint4 xv0, xv1, wv0, wv1;
    {
        int e = q0 * 8;
        xv0 = (gr0 < M) ? (xf32 ? ld8_f32(Xf + (size_t)gr0 * K + e)
                                : ld8_bf16(Xb + (size_t)gr0 * K + e)) : zero4();
        xv1 = (gr1 < M) ? (xf32 ? ld8_f32(Xf + (size_t)gr1 * K + e)
                                : ld8_bf16(Xb + (size_t)gr1 * K + e)) : zero4();
        wv0 = *(const uint4*)(WT + (size_t)(col0 + r0) * K + e);
        wv1 = *(const uint4*)(WT + (size_t)(col0 + r1) * K + e);
    }

    f32x4 acc[4][4] = {};

    for (int k0 = 0; k0 < K; k0 += 32) {
        *(uint4*)&Xs[r0][q0 * 8] = xv0;
        *(uint4*)&Xs[r1][q0 * 8] = xv1;
        *(uint4*)&Ws[r0][q0 * 8] = wv0;
        *(uint4*)&Ws[r1][q0 * 8] = wv1;
        __syncthreads();

        const int k1 = k0 + 32;
        if (k1 < K) {
            int e = k1 + q0 * 8;
            xv0 = (gr0 < M) ? (xf32 ? ld8_f32(Xf + (size_t)gr0 * K + e)
                                    : ld8_bf16(Xb + (size_t)gr0 * K + e)) : zero4();
            xv1 = (gr1 < M) ? (xf32 ? ld8_f32(Xf + (size_t)gr1 * K + e)
                                    : ld8_bf16(Xb + (size_t)gr1 * K + e)) : zero4();
            wv0 = *(const uint4*)(WT + (size_t)(col0 + r0) * K + e);
            wv1 = *(const uint4*)(WT + (size_t)(col0 + r1) * K + e);
        }

        bfrag af[4], bv[4];
#pragma unroll
        for (int i = 0; i < 4; i++)
            af[i] = *(const bfrag*)&Xs[wr + i * 16 + lrow][koff];
#pragma unroll
        for (int j = 0; j < 4; j++)
            bv[j] = *(const bfrag*)&Ws[wc + j * 16 + lrow][koff];
#pragma unroll
        for (int i = 0; i < 4; i++)
#pragma unroll
            for (int j = 0; j < 4; j++)
                acc[i][j] = __builtin_amdgcn_mfma_f32_16x16x32_bf16(
                    af[i], bv[j], acc[i][j], 0, 0, 0);
        __syncthreads();
    }

#pragma unroll
    for (int i = 0; i < 4; i++) {
#pragma unroll
        for (int r = 0; r < 4; r++) {
            int row = row0 + wr + i * 16 + ((lane >> 4) * 4) + r;
            if (row >= M) continue;
            const float s = PRESCALE ? rsqrtf((float)max(cntS[row], 1)) : 1.0f;
#pragma unroll
            for (int j = 0; j < 4; j++) {
                int col = col0 + wc + j * 16 + lrow;
                C[(size_t)row * N + col] = f2bf(acc[i][j][r] * s);
            }
        }
    }
}

// ---------------------------------------------------------------------------
// Mega kernel A (round-0 order, proven ~97us): GEMM blocks first (BW-bound),
// place blocks after (atomic-bound); the atomic EA traffic (~100MB, intrinsic
// to device-scope RMWs) hides under the GEMM stream.  Place-first was 131us.
// ---------------------------------------------------------------------------
__launch_bounds__(256)
__global__ void megaA_kernel(const void* __restrict__ x,
                             const int* __restrict__ ei,
                             const int* __restrict__ flags,
                             const unsigned short* __restrict__ WT,
                             unsigned short* __restrict__ Hbf,
                             int* __restrict__ cntS, int* __restrict__ cntD,
                             unsigned short* __restrict__ esrc_pad, int M) {
    __shared__ unsigned short Xs[128][40];
    __shared__ unsigned short Ws[128][40];
    const int bid = blockIdx.x;
    if (bid < GB_GEMM) {
        gemm_body<true, false>(Xs, Ws, x, flags, WT, nullptr, Hbf,
                               bid & 1, bid >> 1, M, 256);
    } else {
        int e = (bid - GB_GEMM) * 256 + threadIdx.x;
        if (e < N_EDGES) {
            int s, d; load_edge(ei, flags[1], e, s, d);
            atomicAdd(&cntS[s], 1);
            int pos = atomicAdd(&cntD[d], 1);
            if (pos < 64)
                __builtin_nontemporal_store((unsigned short)s,
                                            &esrc_pad[(d << 6) + pos]);
        }
    }
}

// ---------------------------------------------------------------------------
// Accumulation helpers.
// ---------------------------------------------------------------------------
__device__ __forceinline__ void accs(unsigned int u, float s, float& a0, float& a1) {
    a0 = fmaf(s, __uint_as_float(u << 16), a0);
    a1 = fmaf(s, __uint_as_float(u & 0xffff0000u), a1);
}
__device__ __forceinline__ void acc4s(uint4 u, float s, float (&a)[8]) {
    accs(u.x, s, a[0], a[1]); accs(u.y, s, a[2], a[3]);
    accs(u.z, s, a[4], a[5]); accs(u.w, s, a[6], a[7]);
}

// ---------------------------------------------------------------------------
// SPLIT-D gather:  Y[n, half] = relu( sIn*(sum_e [sOut]*H[src, half]) + bias )
// Round-0 parallel structure EXACTLY (per-lane unroll-4 row loads -> same
// outstanding-line count per wave), but each pass touches only half of H's
// columns: per-pass working set 12.8MB (D=256) / 6.4MB (D=128) vs 32MB
// aggregate L2 -> higher L2 hit rate, lower avg miss latency, lower FETCH.
// Halves are time-separated by block ordering (low bids = half 0), like
// megaA's role split.  Cost: edge lists read twice per gather (3.2MB, trivial).
// LQ lanes/node (LQ*16B = half-row bytes).  ESCALE: per-edge rsqrt(cntS)
// (layer 1 only).  OUT: 0 = bf16 only; 2 = fp32 + bf16 mirror.
// ---------------------------------------------------------------------------
template <int LQ, bool ESCALE, int OUT, int DFULL>
__launch_bounds__(256)
__global__ void gather_half_kernel(const int* __restrict__ cntD,
                                   const int* __restrict__ cntS,
                                   const unsigned short* __restrict__ esrc_pad,
                                   const unsigned short* __restrict__ H,
                                   const float* __restrict__ bias,
                                   float* __restrict__ Yf,
                                   unsigned short* __restrict__ Yb,
                                   int M, int nblk_per_pass) {
    constexpr int NPB = 256 / LQ;           // nodes per block
    constexpr int RQ  = DFULL / 8;          // uint4s per full row
    const int half = blockIdx.x / nblk_per_pass;       // 0 or 1
    const int nb   = blockIdx.x - half * nblk_per_pass;
    const int node = nb * NPB + threadIdx.x / LQ;
    const int lane = threadIdx.x % LQ;
    if (node >= M) return;
    const uint4* __restrict__ H4 = (const uint4*)H;
    const unsigned short* __restrict__ ep = esrc_pad + (node << 6);
    const int qoff = half * LQ + lane;      // uint4 index within row

    float a[8] = {};
    const int cn = min(cntD[node], 64);
    int j = 0;
    for (; j + 4 <= cn; j += 4) {
        int s0 = ep[j], s1 = ep[j + 1], s2 = ep[j + 2], s3 = ep[j + 3];
        float w0 = 1.f, w1 = 1.f, w2 = 1.f, w3 = 1.f;
        if (ESCALE) {
            w0 = rsqrtf((float)max(cntS[s0], 1));
            w1 = rsqrtf((float)max(cntS[s1], 1));
            w2 = rsqrtf((float)max(cntS[s2], 1));
            w3 = rsqrtf((float)max(cntS[s3], 1));
        }
        uint4 u0 = H4[(size_t)s0 * RQ + qoff];
        uint4 u1 = H4[(size_t)s1 * RQ + qoff];
        uint4 u2 = H4[(size_t)s2 * RQ + qoff];
        uint4 u3 = H4[(size_t)s3 * RQ + qoff];
        acc4s(u0, w0, a); acc4s(u1, w1, a);
        acc4s(u2, w2, a); acc4s(u3, w3, a);
    }
    for (; j < cn; j++) {
        int s0 = ep[j];
        float w0 = ESCALE ? rsqrtf((float)max(cntS[s0], 1)) : 1.0f;
        uint4 u = H4[(size_t)s0 * RQ + qoff];
        acc4s(u, w0, a);
    }
    const float sc = rsqrtf((float)max(cntD[node], 1));
    const int colb = half * LQ * 8 + lane * 8;          // element col base
    const float* bp = bias + colb;
    float4 b0 = *(const float4*)(bp);
    float4 b1 = *(const float4*)(bp + 4);
    float r0 = fmaxf(fmaf(a[0], sc, b0.x), 0.0f);
    float r1 = fmaxf(fmaf(a[1], sc, b0.y), 0.0f);
    float r2 = fmaxf(fmaf(a[2], sc, b0.z), 0.0f);
    float r3 = fmaxf(fmaf(a[3], sc, b0.w), 0.0f);
    float r4 = fmaxf(fmaf(a[4], sc, b1.x), 0.0f);
    float r5 = fmaxf(fmaf(a[5], sc, b1.y), 0.0f);
    float r6 = fmaxf(fmaf(a[6], sc, b1.z), 0.0f);
    float r7 = fmaxf(fmaf(a[7], sc, b1.w), 0.0f);
    if (OUT == 2) {
        float* yp = Yf + (size_t)node * DFULL + colb;
        float4 o0 = {r0, r1, r2, r3};
        float4 o1 = {r4, r5, r6, r7};
        *(float4*)(yp)     = o0;
        *(float4*)(yp + 4) = o1;
    }
    {
        unsigned short* yp = Yb + (size_t)node * DFULL + colb;
        ushort4 o0, o1;
        o0.x = f2bf(r0); o0.y = f2bf(r1); o0.z = f2bf(r2); o0.w = f2bf(r3);
        o1.x = f2bf(r4); o1.y = f2bf(r5); o1.z = f2bf(r6); o1.w = f2bf(r7);
        *(ushort4*)(yp)     = o0;
        *(ushort4*)(yp + 4) = o1;
    }
}

// Plain conv GEMM (layers 2,3) with output pre-scale by rsqrt(outdeg).
__launch_bounds__(256)
__global__ void mfma_gemm_kernel(const unsigned short* __restrict__ X,
                                 const int* __restrict__ flags,
                                 const unsigned short* __restrict__ WT,
                                 const int* __restrict__ cntS,
                                 unsigned short* __restrict__ C,
                                 int M, int N) {
    __shared__ unsigned short Xs[128][40];
    __shared__ unsigned short Ws[128][40];
    gemm_body<false, true>(Xs, Ws, X, flags, WT, cntS, C,
                           blockIdx.x, blockIdx.y, M, N);
}

// ---------------------------------------------------------------------------
// Fused MLP head:  out[M][64] = relu(X[M][128] @ mW1 + mb1) @ mW2 + mb2
// ---------------------------------------------------------------------------
__launch_bounds__(256)
__global__ void mfma_mlp2_kernel(const unsigned short* __restrict__ X,
                                 const unsigned short* __restrict__ WT1, // [64][128]
                                 const unsigned short* __restrict__ WT2, // [64][64]
                                 const float* __restrict__ b1,
                                 const float* __restrict__ b2,
                                 float* __restrict__ out, int M) {
    __shared__ unsigned short Xs[128][136];
    __shared__ unsigned short W1s[64][136];
    __shared__ unsigned short W2s[64][72];
    const int tid  = threadIdx.x;
    const int lane = tid & 63;
    const int w    = tid >> 6;
    const int lrow = lane & 15;
    const int koff = (lane >> 4) * 8;
    const int row0 = blockIdx.x * 128;

#pragma unroll
    for (int i = 0; i < 8; i++) {
        int c = tid + i * 256;
        int r = c >> 4, q = c & 15;
        int gr = row0 + r;
        uint4 v = (gr < M) ? *(const uint4*)(X + (size_t)gr * 128 + q * 8) : zero4();
        *(uint4*)&Xs[r][q * 8] = v;
    }
#pragma unroll
    for (int i = 0; i < 4; i++) {
        int c = tid + i * 256;
        int n = c >> 4, q = c & 15;
        *(uint4*)&W1s[n][q * 8] = *(const uint4*)(WT1 + (size_t)n * 128 + q * 8);
    }
#pragma unroll
    for (int i = 0; i < 2; i++) {
        int c = tid + i * 256;
        int n = c >> 3, q = c & 7;
        *(uint4*)&W2s[n][q * 8] = *(const uint4*)(WT2 + (size_t)n * 64 + q * 8);
    }
    __syncthreads();

    f32x4 acc[2][4] = {};
#pragma unroll
    for (int k0 = 0; k0 < 128; k0 += 32) {
        bfrag af[2], bv[4];
#pragma unroll
        for (int i = 0; i < 2; i++)
            af[i] = *(const bfrag*)&Xs[w * 32 + i * 16 + lrow][k0 + koff];
#pragma unroll
        for (int j = 0; j < 4; j++)
            bv[j] = *(const bfrag*)&W1s[j * 16 + lrow][k0 + koff];
#pragma unroll
        for (int i = 0; i < 2; i++)
#pragma unroll
            for (int j = 0; j < 4; j++)
                acc[i][j] = __builtin_amdgcn_mfma_f32_16x16x32_bf16(
                    af[i], bv[j], acc[i][j], 0, 0, 0);
    }
    __syncthreads();

#pragma unroll
    for (int i = 0; i < 2; i++) {
#pragma unroll
        for (int r = 0; r < 4; r++) {
            int row = w * 32 + i * 16 + ((lane >> 4) * 4) + r;
#pragma unroll
            for (int j = 0; j < 4; j++) {
                int col = j * 16 + lrow;
                Xs[row][col] = f2bf(fmaxf(acc[i][j][r] + b1[col], 0.0f));
            }
        }
    }
    __syncthreads();

    f32x4 acc2[2][4] = {};
#pragma unroll
    for (int k0 = 0; k0 < 64; k0 += 32) {
        bfrag af[2], bv[4];
#pragma unroll
        for (int i = 0; i < 2; i++)
            af[i] = *(const bfrag*)&Xs[w * 32 + i * 16 + lrow][k0 + koff];
#pragma unroll
        for (int j = 0; j < 4; j++)
            bv[j] = *(const bfrag*)&W2s[j * 16 + lrow][k0 + koff];
#pragma unroll
        for (int i = 0; i < 2; i++)
#pragma unroll
            for (int j = 0; j < 4; j++)
                acc2[i][j] = __builtin_amdgcn_mfma_f32_16x16x32_bf16(
                    af[i], bv[j], acc2[i][j], 0, 0, 0);
    }

#pragma unroll
    for (int i = 0; i < 2; i++) {
#pragma unroll
        for (int r = 0; r < 4; r++) {
            int row = row0 + w * 32 + i * 16 + ((lane >> 4) * 4) + r;
            if (row >= M) continue;
#pragma unroll
            for (int j = 0; j < 4; j++) {
                int col = j * 16 + lrow;
                out[(size_t)row * 64 + col] = acc2[i][j][r] + b2[col];
            }
        }
    }
}

// ---------------------------------------------------------------------------
extern "C" void kernel_launch(void* const* d_in, const int* in_sizes, int n_in,
                              void* d_out, int out_size, void* d_ws, size_t ws_size,
                              hipStream_t stream) {
    const void* x  = d_in[0];
    const int*  ei = (const int*)d_in[1];
    const void *W1 = d_in[2],  *b1 = d_in[3];
    const void *W2 = d_in[4],  *b2 = d_in[5];
    const void *W3 = d_in[6],  *b3 = d_in[7];
    const void *mW1 = d_in[8], *mb1 = d_in[9];
    const void *mW2 = d_in[10],*mb2 = d_in[11];

    // Output: fp32 concatenated (out[50000x64], h_last[50000x128])
    float* out   = (float*)d_out;
    float* out_h = out + (size_t)N_NODES * 64;

    float* ws = (float*)d_ws;
    size_t off = 0;
    int*   flags  = (int*)(ws + off); off += 64;
    int*   cntS   = (int*)(ws + off); off += N_NODES;        // zeroed together
    int*   cntD   = (int*)(ws + off); off += N_NODES;
    unsigned short* esrc_p = (unsigned short*)(ws + off);
    off += (size_t)N_NODES * 32;                             // 50000*64 ushorts
    float* biasd  = ws + off;         off += 768;
    // bias offsets: b1@0 b2@256 b3@512 mb1@640 mb2@704
    off = (off + 63) & ~(size_t)63;
    unsigned short* WT  = (unsigned short*)(ws + off); off += 88448;  // 176896 u16
    // WT segments: conv@0, mWT1@163840, mWT2@172032
    unsigned short* Gbf = (unsigned short*)(ws + off); off += (size_t)N_NODES * 128;
    unsigned short* Hbf = (unsigned short*)(ws + off); off += (size_t)N_NODES * 128;
    unsigned short* hob = (unsigned short*)(ws + off); off += (size_t)N_NODES * 64;  // h_last bf16

    const int M = N_NODES;
    const dim3 blk(256);
    const int gy128 = (M + 127) / 128;        // 391

    // 1) detect + zero counters
    detect_zero_kernel<<<391, blk, 0, stream>>>(
        (const unsigned short*)x, ei, flags, cntS);

    // 2) weight/bias conversion
    cvt_all_kernel<<<(176896 + 255) / 256, blk, 0, stream>>>(
        W1, W2, W3, mW1, mW2, b1, b2, b3, mb1, mb2, flags, WT, biasd);

    // 3) megaA: layer-1 GEMM (x@W1 -> Hbf) || padded-CSR build (GEMM first)
    megaA_kernel<<<GB_GEMM + GB_PLACE, blk, 0, stream>>>(
        x, ei, flags, WT, Hbf, cntS, cntD, esrc_p, M);

    // 4) g1 split-D (ESCALE; H1 unscaled): 2 half-passes x 3125 blocks
    gather_half_kernel<16, true, 0, 256><<<6250, blk, 0, stream>>>(
        cntD, cntS, esrc_p, Hbf, biasd, nullptr, Gbf, M, 3125);

    // 5) layer 2 GEMM (pre-scaled output) + split-D pure-sum gather
    mfma_gemm_kernel<<<dim3(2, gy128), blk, 0, stream>>>(
        Gbf, flags, WT + 65536, cntS, Hbf, M, 256);
    gather_half_kernel<16, false, 0, 256><<<6250, blk, 0, stream>>>(
        cntD, cntS, esrc_p, Hbf, biasd + 256, nullptr, Gbf, M, 3125);

    // 6) layer 3 GEMM (N=128, pre-scaled) + split-D gather -> out_h fp32 + hob
    mfma_gemm_kernel<<<dim3(1, gy128), blk, 0, stream>>>(
        Gbf, flags, WT + 131072, cntS, Hbf, M, 128);
    gather_half_kernel<8, false, 2, 128><<<3126, blk, 0, stream>>>(
        cntD, nullptr, esrc_p, Hbf, biasd + 512, out_h, hob, M, 1563);

    // 7) MLP head fused: out = relu(hob @ mW1 + mb1) @ mW2 + mb2
    mfma_mlp2_kernel<<<gy128, blk, 0, stream>>>(
        hob, WT + 163840, WT + 172032, biasd + 640, biasd + 704, out, M);
}